// Round 7
// baseline (365.338 us; speedup 1.0000x reference)
//
#include <hip/hip_runtime.h>

#define H 1024
#define W 1024
#define NIMG 32
#define NOFF 16
#define NACC 17          // 16 cross terms + 1 sum(s^2)
#define TH 32            // owned rows per tile
#define TW 256           // owned cols per tile
#define TROWS 39         // 32 + 7 halo rows (down only)
#define TSTR 304         // LDS row stride bytes (76 words == 12 mod 32)
#define NBLK (4 * 32 * NIMG)   // 4096 glcm blocks

__device__ __forceinline__ int sdot4i(unsigned a, unsigned b, int c) {
#if __has_builtin(__builtin_amdgcn_sdot4)
    return __builtin_amdgcn_sdot4((int)a, (int)b, c, false);
#else
    c += (int)(signed char)(a)       * (int)(signed char)(b);
    c += (int)(signed char)(a >> 8)  * (int)(signed char)(b >> 8);
    c += (int)(signed char)(a >> 16) * (int)(signed char)(b >> 16);
    c += (int)(signed char)(a >> 24) * (int)(signed char)(b >> 24);
    return c;
#endif
}

__device__ __forceinline__ unsigned funnel(unsigned hi, unsigned lo, int shiftBytes) {
#if __has_builtin(__builtin_amdgcn_alignbit)
    return __builtin_amdgcn_alignbit(hi, lo, shiftBytes * 8);
#else
    unsigned long long pair = (((unsigned long long)hi) << 32) | lo;
    return (unsigned)(pair >> (shiftBytes * 8));
#endif
}

// wave64 sum via DPP butterfly: total lands in lane 63 (pure VALU, no LDS).
__device__ __forceinline__ int wave_sum(int v) {
    v += __builtin_amdgcn_update_dpp(0, v, 0x111, 0xf, 0xf, false); // row_shr:1
    v += __builtin_amdgcn_update_dpp(0, v, 0x112, 0xf, 0xf, false); // row_shr:2
    v += __builtin_amdgcn_update_dpp(0, v, 0x114, 0xf, 0xf, false); // row_shr:4
    v += __builtin_amdgcn_update_dpp(0, v, 0x118, 0xf, 0xf, false); // row_shr:8
    v += __builtin_amdgcn_update_dpp(0, v, 0x142, 0xa, 0xf, false); // row_bcast:15
    v += __builtin_amdgcn_update_dpp(0, v, 0x143, 0xc, 0xf, false); // row_bcast:31
    return v;
}

template <int OC>
__device__ __forceinline__ int dot8(const unsigned* w, const unsigned* aw, int acc) {
#pragma unroll
    for (int m = 0; m < 8; ++m) {
        const int S = 16 + 4 * m + OC;
        unsigned b;
        if ((S & 3) == 0) b = w[S >> 2];
        else              b = funnel(w[(S >> 2) + 1], w[S >> 2], S & 3);
        acc = sdot4i(aw[m], b, acc);
    }
    return acc;
}

// scalar-component assignment only (vector punning into scalar arrays kills SROA)
__device__ __forceinline__ void load16w(const unsigned char* wp, unsigned* w) {
    uint4 t0 = *(const uint4*)(wp);
    uint4 t1 = *(const uint4*)(wp + 16);
    uint4 t2 = *(const uint4*)(wp + 32);
    uint4 t3 = *(const uint4*)(wp + 48);
    w[0] = t0.x;  w[1] = t0.y;  w[2] = t0.z;  w[3] = t0.w;
    w[4] = t1.x;  w[5] = t1.y;  w[6] = t1.z;  w[7] = t1.w;
    w[8] = t2.x;  w[9] = t2.y;  w[10] = t2.z; w[11] = t2.w;
    w[12] = t3.x; w[13] = t3.y; w[14] = t3.z; w[15] = t3.w;
}

__device__ __forceinline__ void load8mid(const unsigned char* wp, unsigned* w) {
    uint4 t1 = *(const uint4*)(wp + 16);
    uint4 t2 = *(const uint4*)(wp + 32);
    w[4] = t1.x;  w[5] = t1.y;  w[6] = t1.z;  w[7] = t1.w;
    w[8] = t2.x;  w[9] = t2.y;  w[10] = t2.z; w[11] = t2.w;
}

__device__ __forceinline__ unsigned pack4(float4 f, float s, float b) {
    unsigned q0 = (unsigned)(int)fmaf(f.x, s, b);
    unsigned q1 = (unsigned)(int)fmaf(f.y, s, b);
    unsigned q2 = (unsigned)(int)fmaf(f.z, s, b);
    unsigned q3 = (unsigned)(int)fmaf(f.w, s, b);
    return (((q0 & 255u)) | ((q1 & 255u) << 8) | ((q2 & 255u) << 16) | ((q3 & 255u) << 24)) ^ 0x80808080u;
}

// ---------------- kernel 1: per-image min/max partials + zero ws accums -------
__global__ __launch_bounds__(256)
void minmax_partial(const float* __restrict__ x, float* __restrict__ pmn,
                    float* __restrict__ pmx, unsigned long long* __restrict__ gacc,
                    int* __restrict__ RowS, int* __restrict__ ColS,
                    unsigned* __restrict__ doneCnt) {
    int img = blockIdx.y;
    int chunk = blockIdx.x;             // 64 chunks of 16384 floats
    int tid = threadIdx.x;
    if (chunk == 0) {                   // ws is poisoned each launch: zero here
        if (tid < NACC) gacc[img * NACC + tid] = 0ull;
        if (tid >= 32 && tid < 46) RowS[img * 14 + tid - 32] = 0;
        if (tid >= 64 && tid < 78) ColS[img * 14 + tid - 64] = 0;
        if (img == 0 && tid == 255) *doneCnt = 0u;
    }
    const float4* b4 = (const float4*)(x + (size_t)img * (H * (size_t)W) +
                                       (size_t)chunk * (H * W / 64));
    float mn = INFINITY, mx = -INFINITY;
    for (int i = tid; i < 4096; i += 256) {
        float4 v = b4[i];
        mn = fminf(mn, fminf(fminf(v.x, v.y), fminf(v.z, v.w)));
        mx = fmaxf(mx, fmaxf(fmaxf(v.x, v.y), fmaxf(v.z, v.w)));
    }
    for (int o = 32; o > 0; o >>= 1) {
        mn = fminf(mn, __shfl_down(mn, o, 64));
        mx = fmaxf(mx, __shfl_down(mx, o, 64));
    }
    __shared__ float smn[4], smx[4];
    int wave = tid >> 6, lane = tid & 63;
    if (lane == 0) { smn[wave] = mn; smx[wave] = mx; }
    __syncthreads();
    if (tid == 0) {
        mn = fminf(fminf(smn[0], smn[1]), fminf(smn[2], smn[3]));
        mx = fmaxf(fmaxf(smx[0], smx[1]), fmaxf(smx[2], smx[3]));
        pmn[img * 64 + chunk] = mn;
        pmx[img * 64 + chunk] = mx;
    }
}

// ---------------- kernel 2: cross terms + s^2 + bands/corners + tail combine --
__global__ __launch_bounds__(256, 8)
void glcm_main(const float* __restrict__ x, const float* __restrict__ pmn,
               const float* __restrict__ pmx, unsigned long long* __restrict__ gacc,
               int* __restrict__ RowS, int* __restrict__ ColS,
               short* __restrict__ cornerWS, unsigned* __restrict__ doneCnt,
               float* __restrict__ out) {
    __shared__ __align__(16) unsigned char tile[TROWS * TSTR];
    __shared__ int wsum[4][NACC];
    __shared__ int sRB[7], sCB[7];
    __shared__ float sms[2];
    __shared__ unsigned sLast;
    int tid = threadIdx.x;
    int img = blockIdx.z;
    int gr0 = blockIdx.y * TH;
    int gc0 = blockIdx.x * TW;
    bool rowTop = (blockIdx.y == 0), rowBot = (blockIdx.y == 31);
    bool colLft = (blockIdx.x == 0), colRgt = (blockIdx.x == 3);

    // per-block min/max finalize (identical op order every block -> identical scale)
    if (tid < 64) {
        float mn = pmn[img * 64 + tid], mx = pmx[img * 64 + tid];
        for (int o = 32; o > 0; o >>= 1) {
            mn = fminf(mn, __shfl_down(mn, o, 64));
            mx = fmaxf(mx, __shfl_down(mx, o, 64));
        }
        if (tid == 0) {
            float sc = 255.0f / (mx - mn);
            sms[0] = sc; sms[1] = -mn * sc;
        }
    }
    if (tid >= 64 && tid < 71) { sRB[tid - 64] = 0; sCB[tid - 64] = 0; }
    __syncthreads();
    float scale = sms[0], nmb = sms[1];
    const float* xi = x + (size_t)img * (H * (size_t)W);

    // coalesced staging: one float4 per lane per step (16B lane stride),
    // pack 4 px -> one ds_write_b32. LDS col c <-> global col gc0-16+c; OOB=0.
    for (int i = tid; i < TROWS * (TSTR / 4); i += 256) {
        int rr = i / (TSTR / 4);
        int c4 = i - rr * (TSTR / 4);
        int grow = gr0 + rr;
        int gcol = gc0 - 16 + 4 * c4;
        unsigned word = 0u;
        if (grow < H && gcol >= 0 && gcol < W) {
            float4 f = *(const float4*)(xi + (size_t)grow * W + gcol);
            word = pack4(f, scale, nmb);
        }
        *(unsigned*)(tile + rr * TSTR + 4 * c4) = word;
    }
    __syncthreads();

    int r = tid >> 3;             // 0..31
    int c0 = (tid & 7) * 32;      // 0..224
    const unsigned char* rowp = tile + r * TSTR + 16 + c0;
    const unsigned char* wbase = tile + r * TSTR + c0;

    uint4 av0 = *(const uint4*)(rowp);
    uint4 av1 = *(const uint4*)(rowp + 16);
    unsigned aw[8];
    aw[0] = av0.x; aw[1] = av0.y; aw[2] = av0.z; aw[3] = av0.w;
    aw[4] = av1.x; aw[5] = av1.y; aw[6] = av1.z; aw[7] = av1.w;

    int acc[NACC];
#pragma unroll
    for (int k = 0; k < NACC; ++k) acc[k] = 0;
#pragma unroll
    for (int m = 0; m < 8; ++m) acc[16] = sdot4i(aw[m], aw[m], acc[16]);

    unsigned w[16];
    {   // delta=0 : oc = 1,3,5,7 (w[4..11]==aw)
#pragma unroll
        for (int i = 0; i < 8; ++i) w[4 + i] = aw[i];
        uint4 t3 = *(const uint4*)(wbase + 48);
        w[12] = t3.x; w[13] = t3.y; w[14] = t3.z; w[15] = t3.w;
        acc[0]  = dot8<1>(w, aw, acc[0]);
        acc[4]  = dot8<3>(w, aw, acc[4]);
        acc[8]  = dot8<5>(w, aw, acc[8]);
        acc[12] = dot8<7>(w, aw, acc[12]);
    }
    {   // delta=1 : oc = 1,0,-1
        load16w(wbase + 1 * TSTR, w);
        acc[1] = dot8<1>(w, aw, acc[1]);
        acc[2] = dot8<0>(w, aw, acc[2]);
        acc[3] = dot8<-1>(w, aw, acc[3]);
    }
    {   // delta=2 : oc = 2,-2
        load16w(wbase + 2 * TSTR, w);
        acc[5] = dot8<2>(w, aw, acc[5]);
        acc[7] = dot8<-2>(w, aw, acc[7]);
    }
    {   // delta=3 : oc = 0
        load8mid(wbase + 3 * TSTR, w);
        acc[6] = dot8<0>(w, aw, acc[6]);
    }
    {   // delta=4 : oc = 4,-4
        load16w(wbase + 4 * TSTR, w);
        acc[9]  = dot8<4>(w, aw, acc[9]);
        acc[11] = dot8<-4>(w, aw, acc[11]);
    }
    {   // delta=5 : oc = 0,5,-5
        load16w(wbase + 5 * TSTR, w);
        acc[10] = dot8<0>(w, aw, acc[10]);
        acc[13] = dot8<5>(w, aw, acc[13]);
        acc[15] = dot8<-5>(w, aw, acc[15]);
    }
    {   // delta=7 : oc = 0
        load8mid(wbase + 7 * TSTR, w);
        acc[14] = dot8<0>(w, aw, acc[14]);
    }

    // wave reduce via DPP (no LDS serialization), lane 63 holds totals
    int wv = tid >> 6, lane = tid & 63;
#pragma unroll
    for (int k = 0; k < NACC; ++k) {
        int s = wave_sum(acc[k]);
        if (lane == 63) wsum[wv][k] = s;
    }

    // border band sums of s^2 from staged tile
    if (rowTop || rowBot) {
        int base = rowTop ? 0 : (TH - 7);
        for (int idx = tid; idx < 7 * 64; idx += 256) {
            int rr = idx >> 6, ww = idx & 63;
            unsigned v = *(const unsigned*)(tile + (base + rr) * TSTR + 16 + 4 * ww);
            atomicAdd(&sRB[rr], sdot4i(v, v, 0));
        }
    }
    if (colLft || colRgt) {
        int cb = colLft ? 16 : 265;
        if (tid < 7 * TH) {
            int rr = tid / 7, j = tid - rr * 7;
            int s = (int)(signed char)tile[rr * TSTR + cb + j];
            atomicAdd(&sCB[j], s * s);
        }
    }
    // corner 7x7 s^2 patches -> ws (0=TL,1=TR,2=BL,3=BR, oriented to corner)
    if (tid < 49) {
        int i = tid / 7, j = tid - i * 7;
        if (rowTop && colLft) {
            int s = (int)(signed char)tile[i * TSTR + 16 + j];
            cornerWS[(img * 4 + 0) * 49 + tid] = (short)(s * s);
        }
        if (rowTop && colRgt) {
            int s = (int)(signed char)tile[i * TSTR + 271 - j];
            cornerWS[(img * 4 + 1) * 49 + tid] = (short)(s * s);
        }
        if (rowBot && colLft) {
            int s = (int)(signed char)tile[(TH - 1 - i) * TSTR + 16 + j];
            cornerWS[(img * 4 + 2) * 49 + tid] = (short)(s * s);
        }
        if (rowBot && colRgt) {
            int s = (int)(signed char)tile[(TH - 1 - i) * TSTR + 271 - j];
            cornerWS[(img * 4 + 3) * 49 + tid] = (short)(s * s);
        }
    }
    __syncthreads();
    if (tid < NACC) {
        int s = wsum[0][tid] + wsum[1][tid] + wsum[2][tid] + wsum[3][tid];
        atomicAdd(&gacc[img * NACC + tid], (unsigned long long)(long long)s);
    }
    if (tid < 7) {
        if (rowTop) atomicAdd(&RowS[img * 14 + tid], sRB[tid]);
        if (rowBot) atomicAdd(&RowS[img * 14 + 7 + tid], sRB[tid]);
        if (colLft) atomicAdd(&ColS[img * 14 + tid], sCB[tid]);
        if (colRgt) atomicAdd(&ColS[img * 14 + 7 + tid], sCB[tid]);
    }

    // ---- threadfence reduction: the last block to finish combines everything ----
    __syncthreads();
    if (tid == 0) {
        __threadfence();                         // release this block's work
        sLast = atomicAdd(doneCnt, 1u);
    }
    __syncthreads();
    if (sLast == NBLK - 1) {
        __threadfence();                         // acquire all blocks' work
        const int ORO[16] = {0,1,1,1, 0,2,3,2, 0,4,5,4, 0,5,7,5};
        const int OCO[16] = {1,1,0,-1, 3,2,0,-2, 5,4,0,-4, 7,5,0,-5};
        for (int o = tid; o < NIMG * NOFF; o += 256) {
            int im = o >> 4, k = o & 15;
            int orr = ORO[k], oc = OCO[k], aoc = oc < 0 ? -oc : oc;
            long long RT = 0, RB = 0, CL = 0, CR = 0;
            for (int i = 0; i < orr; ++i) {
                RT += RowS[im * 14 + i];
                RB += RowS[im * 14 + 13 - i];
            }
            for (int i = 0; i < aoc; ++i) {
                CL += ColS[im * 14 + i];
                CR += ColS[im * 14 + 13 - i];
            }
            long long CA = oc > 0 ? CR : CL;
            long long CB = oc > 0 ? CL : CR;
            const short* pa = cornerWS + (im * 4 + (oc >= 0 ? 3 : 2)) * 49;
            const short* pb = cornerWS + (im * 4 + (oc >= 0 ? 0 : 1)) * 49;
            long long PSa = 0, PSb = 0;
            for (int i = 0; i < orr; ++i)
                for (int j = 0; j < aoc; ++j) {
                    PSa += pa[i * 7 + j];
                    PSb += pb[i * 7 + j];
                }
            long long corr = -(RT + RB + CA + CB) + PSa + PSb;
            long long cross = (long long)gacc[im * NACC + k];
            long long tsum  = (long long)gacc[im * NACC + 16];
            long long num = 2 * tsum + corr - 2 * cross;
            double n = (double)(H - orr) * (double)(W - aoc);
            out[o] = (float)((double)num / n);
        }
    }
}

extern "C" void kernel_launch(void* const* d_in, const int* in_sizes, int n_in,
                              void* d_out, int out_size, void* d_ws, size_t ws_size,
                              hipStream_t stream) {
    const float* x = (const float*)d_in[0];
    float* out = (float*)d_out;
    char* ws = (char*)d_ws;
    float* pmn = (float*)ws;                                       // 2048 f   @0
    float* pmx = (float*)(ws + 8192);                              // 2048 f   @8192
    unsigned long long* gacc = (unsigned long long*)(ws + 16384);  // 32*17 u64
    int* RowS = (int*)(ws + 20736);                                // 32*14 int
    int* ColS = (int*)(ws + 22528);                                // 32*14 int
    short* cornerWS = (short*)(ws + 24576);                        // 32*4*49 short
    unsigned* doneCnt = (unsigned*)(ws + 38912);                   // 1 u32

    minmax_partial<<<dim3(64, NIMG), 256, 0, stream>>>(x, pmn, pmx, gacc,
                                                       RowS, ColS, doneCnt);
    glcm_main<<<dim3(4, 32, NIMG), 256, 0, stream>>>(x, pmn, pmx, gacc, RowS,
                                                     ColS, cornerWS, doneCnt, out);
}

// Round 8
// 330.181 us; speedup vs baseline: 1.1065x; 1.1065x over previous
//
#include <hip/hip_runtime.h>

#define H 1024
#define W 1024
#define NIMG 32
#define NOFF 16
#define NACC 17          // 16 cross terms + 1 sum(s^2)
#define TH 32            // owned rows per tile
#define TW 256           // owned cols per tile
#define TROWS 39         // 32 + 7 halo rows (down only)
#define TSTR 304         // LDS row stride bytes (76 words == 12 mod 32)
#define NBLK (4 * 32 * NIMG)   // 4096 glcm blocks

__device__ __forceinline__ int sdot4i(unsigned a, unsigned b, int c) {
#if __has_builtin(__builtin_amdgcn_sdot4)
    return __builtin_amdgcn_sdot4((int)a, (int)b, c, false);
#else
    c += (int)(signed char)(a)       * (int)(signed char)(b);
    c += (int)(signed char)(a >> 8)  * (int)(signed char)(b >> 8);
    c += (int)(signed char)(a >> 16) * (int)(signed char)(b >> 16);
    c += (int)(signed char)(a >> 24) * (int)(signed char)(b >> 24);
    return c;
#endif
}

__device__ __forceinline__ unsigned funnel(unsigned hi, unsigned lo, int shiftBytes) {
#if __has_builtin(__builtin_amdgcn_alignbit)
    return __builtin_amdgcn_alignbit(hi, lo, shiftBytes * 8);
#else
    unsigned long long pair = (((unsigned long long)hi) << 32) | lo;
    return (unsigned)(pair >> (shiftBytes * 8));
#endif
}

// wave64 sum via DPP butterfly: total lands in lane 63 (pure VALU, no LDS).
__device__ __forceinline__ int wave_sum(int v) {
    v += __builtin_amdgcn_update_dpp(0, v, 0x111, 0xf, 0xf, false); // row_shr:1
    v += __builtin_amdgcn_update_dpp(0, v, 0x112, 0xf, 0xf, false); // row_shr:2
    v += __builtin_amdgcn_update_dpp(0, v, 0x114, 0xf, 0xf, false); // row_shr:4
    v += __builtin_amdgcn_update_dpp(0, v, 0x118, 0xf, 0xf, false); // row_shr:8
    v += __builtin_amdgcn_update_dpp(0, v, 0x142, 0xa, 0xf, false); // row_bcast:15
    v += __builtin_amdgcn_update_dpp(0, v, 0x143, 0xc, 0xf, false); // row_bcast:31
    return v;
}

template <int OC>
__device__ __forceinline__ int dot8(const unsigned* w, const unsigned* aw, int acc) {
#pragma unroll
    for (int m = 0; m < 8; ++m) {
        const int S = 16 + 4 * m + OC;
        unsigned b;
        if ((S & 3) == 0) b = w[S >> 2];
        else              b = funnel(w[(S >> 2) + 1], w[S >> 2], S & 3);
        acc = sdot4i(aw[m], b, acc);
    }
    return acc;
}

// scalar-component assignment only (vector punning into scalar arrays kills SROA)
__device__ __forceinline__ void load16w(const unsigned char* wp, unsigned* w) {
    uint4 t0 = *(const uint4*)(wp);
    uint4 t1 = *(const uint4*)(wp + 16);
    uint4 t2 = *(const uint4*)(wp + 32);
    uint4 t3 = *(const uint4*)(wp + 48);
    w[0] = t0.x;  w[1] = t0.y;  w[2] = t0.z;  w[3] = t0.w;
    w[4] = t1.x;  w[5] = t1.y;  w[6] = t1.z;  w[7] = t1.w;
    w[8] = t2.x;  w[9] = t2.y;  w[10] = t2.z; w[11] = t2.w;
    w[12] = t3.x; w[13] = t3.y; w[14] = t3.z; w[15] = t3.w;
}

__device__ __forceinline__ void load8mid(const unsigned char* wp, unsigned* w) {
    uint4 t1 = *(const uint4*)(wp + 16);
    uint4 t2 = *(const uint4*)(wp + 32);
    w[4] = t1.x;  w[5] = t1.y;  w[6] = t1.z;  w[7] = t1.w;
    w[8] = t2.x;  w[9] = t2.y;  w[10] = t2.z; w[11] = t2.w;
}

__device__ __forceinline__ unsigned pack4(float4 f, float s, float b) {
    unsigned q0 = (unsigned)(int)fmaf(f.x, s, b);
    unsigned q1 = (unsigned)(int)fmaf(f.y, s, b);
    unsigned q2 = (unsigned)(int)fmaf(f.z, s, b);
    unsigned q3 = (unsigned)(int)fmaf(f.w, s, b);
    return (((q0 & 255u)) | ((q1 & 255u) << 8) | ((q2 & 255u) << 16) | ((q3 & 255u) << 24)) ^ 0x80808080u;
}

// ---------------- kernel 1: per-image min/max partials + zero ws accums -------
__global__ __launch_bounds__(256)
void minmax_partial(const float* __restrict__ x, float* __restrict__ pmn,
                    float* __restrict__ pmx, unsigned long long* __restrict__ gacc,
                    int* __restrict__ RowS, int* __restrict__ ColS,
                    unsigned* __restrict__ doneCnt) {
    int img = blockIdx.y;
    int chunk = blockIdx.x;             // 64 chunks of 16384 floats
    int tid = threadIdx.x;
    if (chunk == 0) {                   // ws is poisoned each launch: zero here
        if (tid < NACC) gacc[img * NACC + tid] = 0ull;
        if (tid >= 32 && tid < 46) RowS[img * 14 + tid - 32] = 0;
        if (tid >= 64 && tid < 78) ColS[img * 14 + tid - 64] = 0;
        if (img == 0 && tid == 255) *doneCnt = 0u;
    }
    const float4* b4 = (const float4*)(x + (size_t)img * (H * (size_t)W) +
                                       (size_t)chunk * (H * W / 64));
    float mn = INFINITY, mx = -INFINITY;
    for (int i = tid; i < 4096; i += 256) {
        float4 v = b4[i];
        mn = fminf(mn, fminf(fminf(v.x, v.y), fminf(v.z, v.w)));
        mx = fmaxf(mx, fmaxf(fmaxf(v.x, v.y), fmaxf(v.z, v.w)));
    }
    for (int o = 32; o > 0; o >>= 1) {
        mn = fminf(mn, __shfl_down(mn, o, 64));
        mx = fmaxf(mx, __shfl_down(mx, o, 64));
    }
    __shared__ float smn[4], smx[4];
    int wave = tid >> 6, lane = tid & 63;
    if (lane == 0) { smn[wave] = mn; smx[wave] = mx; }
    __syncthreads();
    if (tid == 0) {
        mn = fminf(fminf(smn[0], smn[1]), fminf(smn[2], smn[3]));
        mx = fmaxf(fmaxf(smx[0], smx[1]), fmaxf(smx[2], smx[3]));
        pmn[img * 64 + chunk] = mn;
        pmx[img * 64 + chunk] = mx;
    }
}

// ---------------- kernel 2: cross terms + s^2 + bands/corners + tail combine --
__global__ __launch_bounds__(256)
void glcm_main(const float* __restrict__ x, const float* __restrict__ pmn,
               const float* __restrict__ pmx, unsigned long long* __restrict__ gacc,
               int* __restrict__ RowS, int* __restrict__ ColS,
               short* __restrict__ cornerWS, unsigned* __restrict__ doneCnt,
               float* __restrict__ out) {
    __shared__ __align__(16) unsigned char tile[TROWS * TSTR];
    __shared__ int wsum[4][NACC];
    __shared__ int sRB[7], sCB[7];
    __shared__ float sms[2];
    __shared__ unsigned sLast;
    int tid = threadIdx.x;
    int img = blockIdx.z;
    int gr0 = blockIdx.y * TH;
    int gc0 = blockIdx.x * TW;
    bool rowTop = (blockIdx.y == 0), rowBot = (blockIdx.y == 31);
    bool colLft = (blockIdx.x == 0), colRgt = (blockIdx.x == 3);

    // per-block min/max finalize (identical op order every block -> identical scale)
    if (tid < 64) {
        float mn = pmn[img * 64 + tid], mx = pmx[img * 64 + tid];
        for (int o = 32; o > 0; o >>= 1) {
            mn = fminf(mn, __shfl_down(mn, o, 64));
            mx = fmaxf(mx, __shfl_down(mx, o, 64));
        }
        if (tid == 0) {
            float sc = 255.0f / (mx - mn);
            sms[0] = sc; sms[1] = -mn * sc;
        }
    }
    if (tid >= 64 && tid < 71) { sRB[tid - 64] = 0; sCB[tid - 64] = 0; }
    __syncthreads();
    float scale = sms[0], nmb = sms[1];
    const float* xi = x + (size_t)img * (H * (size_t)W);

    // coalesced staging: one float4 per lane per step (16B lane stride),
    // pack 4 px -> one ds_write_b32. LDS col c <-> global col gc0-16+c; OOB=0.
    for (int i = tid; i < TROWS * (TSTR / 4); i += 256) {
        int rr = i / (TSTR / 4);
        int c4 = i - rr * (TSTR / 4);
        int grow = gr0 + rr;
        int gcol = gc0 - 16 + 4 * c4;
        unsigned word = 0u;
        if (grow < H && gcol >= 0 && gcol < W) {
            float4 f = *(const float4*)(xi + (size_t)grow * W + gcol);
            word = pack4(f, scale, nmb);
        }
        *(unsigned*)(tile + rr * TSTR + 4 * c4) = word;
    }
    __syncthreads();

    int r = tid >> 3;             // 0..31
    int c0 = (tid & 7) * 32;      // 0..224
    const unsigned char* rowp = tile + r * TSTR + 16 + c0;
    const unsigned char* wbase = tile + r * TSTR + c0;

    uint4 av0 = *(const uint4*)(rowp);
    uint4 av1 = *(const uint4*)(rowp + 16);
    unsigned aw[8];
    aw[0] = av0.x; aw[1] = av0.y; aw[2] = av0.z; aw[3] = av0.w;
    aw[4] = av1.x; aw[5] = av1.y; aw[6] = av1.z; aw[7] = av1.w;

    int acc[NACC];
#pragma unroll
    for (int k = 0; k < NACC; ++k) acc[k] = 0;
#pragma unroll
    for (int m = 0; m < 8; ++m) acc[16] = sdot4i(aw[m], aw[m], acc[16]);

    unsigned w[16];
    {   // delta=0 : oc = 1,3,5,7 (w[4..11]==aw)
#pragma unroll
        for (int i = 0; i < 8; ++i) w[4 + i] = aw[i];
        uint4 t3 = *(const uint4*)(wbase + 48);
        w[12] = t3.x; w[13] = t3.y; w[14] = t3.z; w[15] = t3.w;
        acc[0]  = dot8<1>(w, aw, acc[0]);
        acc[4]  = dot8<3>(w, aw, acc[4]);
        acc[8]  = dot8<5>(w, aw, acc[8]);
        acc[12] = dot8<7>(w, aw, acc[12]);
    }
    {   // delta=1 : oc = 1,0,-1
        load16w(wbase + 1 * TSTR, w);
        acc[1] = dot8<1>(w, aw, acc[1]);
        acc[2] = dot8<0>(w, aw, acc[2]);
        acc[3] = dot8<-1>(w, aw, acc[3]);
    }
    {   // delta=2 : oc = 2,-2
        load16w(wbase + 2 * TSTR, w);
        acc[5] = dot8<2>(w, aw, acc[5]);
        acc[7] = dot8<-2>(w, aw, acc[7]);
    }
    {   // delta=3 : oc = 0
        load8mid(wbase + 3 * TSTR, w);
        acc[6] = dot8<0>(w, aw, acc[6]);
    }
    {   // delta=4 : oc = 4,-4
        load16w(wbase + 4 * TSTR, w);
        acc[9]  = dot8<4>(w, aw, acc[9]);
        acc[11] = dot8<-4>(w, aw, acc[11]);
    }
    {   // delta=5 : oc = 0,5,-5
        load16w(wbase + 5 * TSTR, w);
        acc[10] = dot8<0>(w, aw, acc[10]);
        acc[13] = dot8<5>(w, aw, acc[13]);
        acc[15] = dot8<-5>(w, aw, acc[15]);
    }
    {   // delta=7 : oc = 0
        load8mid(wbase + 7 * TSTR, w);
        acc[14] = dot8<0>(w, aw, acc[14]);
    }

    // wave reduce via DPP (no LDS serialization), lane 63 holds totals
    int wv = tid >> 6, lane = tid & 63;
#pragma unroll
    for (int k = 0; k < NACC; ++k) {
        int s = wave_sum(acc[k]);
        if (lane == 63) wsum[wv][k] = s;
    }

    // border band sums of s^2 from staged tile
    if (rowTop || rowBot) {
        int base = rowTop ? 0 : (TH - 7);
        for (int idx = tid; idx < 7 * 64; idx += 256) {
            int rr = idx >> 6, ww = idx & 63;
            unsigned v = *(const unsigned*)(tile + (base + rr) * TSTR + 16 + 4 * ww);
            atomicAdd(&sRB[rr], sdot4i(v, v, 0));
        }
    }
    if (colLft || colRgt) {
        int cb = colLft ? 16 : 265;
        if (tid < 7 * TH) {
            int rr = tid / 7, j = tid - rr * 7;
            int s = (int)(signed char)tile[rr * TSTR + cb + j];
            atomicAdd(&sCB[j], s * s);
        }
    }
    // corner 7x7 s^2 patches -> ws (0=TL,1=TR,2=BL,3=BR, oriented to corner)
    if (tid < 49) {
        int i = tid / 7, j = tid - i * 7;
        if (rowTop && colLft) {
            int s = (int)(signed char)tile[i * TSTR + 16 + j];
            cornerWS[(img * 4 + 0) * 49 + tid] = (short)(s * s);
        }
        if (rowTop && colRgt) {
            int s = (int)(signed char)tile[i * TSTR + 271 - j];
            cornerWS[(img * 4 + 1) * 49 + tid] = (short)(s * s);
        }
        if (rowBot && colLft) {
            int s = (int)(signed char)tile[(TH - 1 - i) * TSTR + 16 + j];
            cornerWS[(img * 4 + 2) * 49 + tid] = (short)(s * s);
        }
        if (rowBot && colRgt) {
            int s = (int)(signed char)tile[(TH - 1 - i) * TSTR + 271 - j];
            cornerWS[(img * 4 + 3) * 49 + tid] = (short)(s * s);
        }
    }
    __syncthreads();
    if (tid < NACC) {
        int s = wsum[0][tid] + wsum[1][tid] + wsum[2][tid] + wsum[3][tid];
        atomicAdd(&gacc[img * NACC + tid], (unsigned long long)(long long)s);
    }
    if (tid < 7) {
        if (rowTop) atomicAdd(&RowS[img * 14 + tid], sRB[tid]);
        if (rowBot) atomicAdd(&RowS[img * 14 + 7 + tid], sRB[tid]);
        if (colLft) atomicAdd(&ColS[img * 14 + tid], sCB[tid]);
        if (colRgt) atomicAdd(&ColS[img * 14 + 7 + tid], sCB[tid]);
    }

    // ---- threadfence reduction: the last block to finish combines everything ----
    __syncthreads();
    if (tid == 0) {
        __threadfence();                         // release this block's work
        sLast = atomicAdd(doneCnt, 1u);
    }
    __syncthreads();
    if (sLast == NBLK - 1) {
        __threadfence();                         // acquire all blocks' work
        const int ORO[16] = {0,1,1,1, 0,2,3,2, 0,4,5,4, 0,5,7,5};
        const int OCO[16] = {1,1,0,-1, 3,2,0,-2, 5,4,0,-4, 7,5,0,-5};
        for (int o = tid; o < NIMG * NOFF; o += 256) {
            int im = o >> 4, k = o & 15;
            int orr = ORO[k], oc = OCO[k], aoc = oc < 0 ? -oc : oc;
            long long RT = 0, RB = 0, CL = 0, CR = 0;
            for (int i = 0; i < orr; ++i) {
                RT += RowS[im * 14 + i];
                RB += RowS[im * 14 + 13 - i];
            }
            for (int i = 0; i < aoc; ++i) {
                CL += ColS[im * 14 + i];
                CR += ColS[im * 14 + 13 - i];
            }
            long long CA = oc > 0 ? CR : CL;
            long long CB = oc > 0 ? CL : CR;
            const short* pa = cornerWS + (im * 4 + (oc >= 0 ? 3 : 2)) * 49;
            const short* pb = cornerWS + (im * 4 + (oc >= 0 ? 0 : 1)) * 49;
            long long PSa = 0, PSb = 0;
            for (int i = 0; i < orr; ++i)
                for (int j = 0; j < aoc; ++j) {
                    PSa += pa[i * 7 + j];
                    PSb += pb[i * 7 + j];
                }
            long long corr = -(RT + RB + CA + CB) + PSa + PSb;
            long long cross = (long long)gacc[im * NACC + k];
            long long tsum  = (long long)gacc[im * NACC + 16];
            long long num = 2 * tsum + corr - 2 * cross;
            double n = (double)(H - orr) * (double)(W - aoc);
            out[o] = (float)((double)num / n);
        }
    }
}

extern "C" void kernel_launch(void* const* d_in, const int* in_sizes, int n_in,
                              void* d_out, int out_size, void* d_ws, size_t ws_size,
                              hipStream_t stream) {
    const float* x = (const float*)d_in[0];
    float* out = (float*)d_out;
    char* ws = (char*)d_ws;
    float* pmn = (float*)ws;                                       // 2048 f   @0
    float* pmx = (float*)(ws + 8192);                              // 2048 f   @8192
    unsigned long long* gacc = (unsigned long long*)(ws + 16384);  // 32*17 u64
    int* RowS = (int*)(ws + 20736);                                // 32*14 int
    int* ColS = (int*)(ws + 22528);                                // 32*14 int
    short* cornerWS = (short*)(ws + 24576);                        // 32*4*49 short
    unsigned* doneCnt = (unsigned*)(ws + 38912);                   // 1 u32

    minmax_partial<<<dim3(64, NIMG), 256, 0, stream>>>(x, pmn, pmx, gacc,
                                                       RowS, ColS, doneCnt);
    glcm_main<<<dim3(4, 32, NIMG), 256, 0, stream>>>(x, pmn, pmx, gacc, RowS,
                                                     ColS, cornerWS, doneCnt, out);
}

// Round 9
// 241.648 us; speedup vs baseline: 1.5119x; 1.3664x over previous
//
#include <hip/hip_runtime.h>

#define H 1024
#define W 1024
#define NIMG 32
#define NOFF 16
#define NACC 17          // 16 cross terms + 1 sum(s^2)
#define TH 32            // owned rows per tile
#define TW 256           // owned cols per tile
#define TROWS 39         // 32 + 7 halo rows (down only)
#define TSTR 304         // LDS row stride bytes (76 words == 12 mod 32)

__device__ __forceinline__ int sdot4i(unsigned a, unsigned b, int c) {
#if __has_builtin(__builtin_amdgcn_sdot4)
    return __builtin_amdgcn_sdot4((int)a, (int)b, c, false);
#else
    c += (int)(signed char)(a)       * (int)(signed char)(b);
    c += (int)(signed char)(a >> 8)  * (int)(signed char)(b >> 8);
    c += (int)(signed char)(a >> 16) * (int)(signed char)(b >> 16);
    c += (int)(signed char)(a >> 24) * (int)(signed char)(b >> 24);
    return c;
#endif
}

__device__ __forceinline__ unsigned funnel(unsigned hi, unsigned lo, int shiftBytes) {
#if __has_builtin(__builtin_amdgcn_alignbit)
    return __builtin_amdgcn_alignbit(hi, lo, shiftBytes * 8);
#else
    unsigned long long pair = (((unsigned long long)hi) << 32) | lo;
    return (unsigned)(pair >> (shiftBytes * 8));
#endif
}

// wave64 sum via DPP butterfly: total lands in lane 63 (pure VALU, no LDS).
__device__ __forceinline__ int wave_sum(int v) {
    v += __builtin_amdgcn_update_dpp(0, v, 0x111, 0xf, 0xf, false); // row_shr:1
    v += __builtin_amdgcn_update_dpp(0, v, 0x112, 0xf, 0xf, false); // row_shr:2
    v += __builtin_amdgcn_update_dpp(0, v, 0x114, 0xf, 0xf, false); // row_shr:4
    v += __builtin_amdgcn_update_dpp(0, v, 0x118, 0xf, 0xf, false); // row_shr:8
    v += __builtin_amdgcn_update_dpp(0, v, 0x142, 0xa, 0xf, false); // row_bcast:15
    v += __builtin_amdgcn_update_dpp(0, v, 0x143, 0xc, 0xf, false); // row_bcast:31
    return v;
}

template <int OC>
__device__ __forceinline__ int dot8(const unsigned* w, const unsigned* aw, int acc) {
#pragma unroll
    for (int m = 0; m < 8; ++m) {
        const int S = 16 + 4 * m + OC;
        unsigned b;
        if ((S & 3) == 0) b = w[S >> 2];
        else              b = funnel(w[(S >> 2) + 1], w[S >> 2], S & 3);
        acc = sdot4i(aw[m], b, acc);
    }
    return acc;
}

// scalar-component assignment only (vector punning into scalar arrays kills SROA)
__device__ __forceinline__ void load16w(const unsigned char* wp, unsigned* w) {
    uint4 t0 = *(const uint4*)(wp);
    uint4 t1 = *(const uint4*)(wp + 16);
    uint4 t2 = *(const uint4*)(wp + 32);
    uint4 t3 = *(const uint4*)(wp + 48);
    w[0] = t0.x;  w[1] = t0.y;  w[2] = t0.z;  w[3] = t0.w;
    w[4] = t1.x;  w[5] = t1.y;  w[6] = t1.z;  w[7] = t1.w;
    w[8] = t2.x;  w[9] = t2.y;  w[10] = t2.z; w[11] = t2.w;
    w[12] = t3.x; w[13] = t3.y; w[14] = t3.z; w[15] = t3.w;
}

__device__ __forceinline__ void load8mid(const unsigned char* wp, unsigned* w) {
    uint4 t1 = *(const uint4*)(wp + 16);
    uint4 t2 = *(const uint4*)(wp + 32);
    w[4] = t1.x;  w[5] = t1.y;  w[6] = t1.z;  w[7] = t1.w;
    w[8] = t2.x;  w[9] = t2.y;  w[10] = t2.z; w[11] = t2.w;
}

__device__ __forceinline__ unsigned pack4(float4 f, float s, float b) {
    unsigned q0 = (unsigned)(int)fmaf(f.x, s, b);
    unsigned q1 = (unsigned)(int)fmaf(f.y, s, b);
    unsigned q2 = (unsigned)(int)fmaf(f.z, s, b);
    unsigned q3 = (unsigned)(int)fmaf(f.w, s, b);
    return (((q0 & 255u)) | ((q1 & 255u) << 8) | ((q2 & 255u) << 16) | ((q3 & 255u) << 24)) ^ 0x80808080u;
}

// ---------------- kernel 1: per-image min/max partials + zero ws accums -------
__global__ __launch_bounds__(256)
void minmax_partial(const float* __restrict__ x, float* __restrict__ pmn,
                    float* __restrict__ pmx, unsigned long long* __restrict__ gacc,
                    int* __restrict__ RowS, int* __restrict__ ColS) {
    int img = blockIdx.y;
    int chunk = blockIdx.x;             // 64 chunks of 16384 floats
    int tid = threadIdx.x;
    if (chunk == 0) {                   // ws is poisoned each launch: zero here
        if (tid < NACC) gacc[img * NACC + tid] = 0ull;
        if (tid >= 32 && tid < 46) RowS[img * 14 + tid - 32] = 0;
        if (tid >= 64 && tid < 78) ColS[img * 14 + tid - 64] = 0;
    }
    const float4* b4 = (const float4*)(x + (size_t)img * (H * (size_t)W) +
                                       (size_t)chunk * (H * W / 64));
    float mn = INFINITY, mx = -INFINITY;
    for (int i = tid; i < 4096; i += 256) {
        float4 v = b4[i];
        mn = fminf(mn, fminf(fminf(v.x, v.y), fminf(v.z, v.w)));
        mx = fmaxf(mx, fmaxf(fmaxf(v.x, v.y), fmaxf(v.z, v.w)));
    }
    for (int o = 32; o > 0; o >>= 1) {
        mn = fminf(mn, __shfl_down(mn, o, 64));
        mx = fmaxf(mx, __shfl_down(mx, o, 64));
    }
    __shared__ float smn[4], smx[4];
    int wave = tid >> 6, lane = tid & 63;
    if (lane == 0) { smn[wave] = mn; smx[wave] = mx; }
    __syncthreads();
    if (tid == 0) {
        mn = fminf(fminf(smn[0], smn[1]), fminf(smn[2], smn[3]));
        mx = fmaxf(fmaxf(smx[0], smx[1]), fmaxf(smx[2], smx[3]));
        pmn[img * 64 + chunk] = mn;
        pmx[img * 64 + chunk] = mx;
    }
}

// ---------------- kernel 2: cross terms + s^2 + bands/corners -----------------
__global__ __launch_bounds__(256)
void glcm_main(const float* __restrict__ x, const float* __restrict__ pmn,
               const float* __restrict__ pmx, unsigned long long* __restrict__ gacc,
               int* __restrict__ RowS, int* __restrict__ ColS,
               short* __restrict__ cornerWS) {
    __shared__ __align__(16) unsigned char tile[TROWS * TSTR];
    __shared__ int wsum[4][NACC];
    __shared__ int sRB[7], sCB[7];
    __shared__ float sms[2];
    int tid = threadIdx.x;
    int img = blockIdx.z;
    int gr0 = blockIdx.y * TH;
    int gc0 = blockIdx.x * TW;
    bool rowTop = (blockIdx.y == 0), rowBot = (blockIdx.y == 31);
    bool colLft = (blockIdx.x == 0), colRgt = (blockIdx.x == 3);

    // per-block min/max finalize (identical op order every block -> identical scale)
    if (tid < 64) {
        float mn = pmn[img * 64 + tid], mx = pmx[img * 64 + tid];
        for (int o = 32; o > 0; o >>= 1) {
            mn = fminf(mn, __shfl_down(mn, o, 64));
            mx = fmaxf(mx, __shfl_down(mx, o, 64));
        }
        if (tid == 0) {
            float sc = 255.0f / (mx - mn);
            sms[0] = sc; sms[1] = -mn * sc;
        }
    }
    if (tid >= 64 && tid < 71) { sRB[tid - 64] = 0; sCB[tid - 64] = 0; }
    __syncthreads();
    float scale = sms[0], nmb = sms[1];
    const float* xi = x + (size_t)img * (H * (size_t)W);

    // coalesced staging: one float4 per lane per step (16B lane stride),
    // pack 4 px -> one ds_write_b32. LDS col c <-> global col gc0-16+c; OOB=0.
    for (int i = tid; i < TROWS * (TSTR / 4); i += 256) {
        int rr = i / (TSTR / 4);
        int c4 = i - rr * (TSTR / 4);
        int grow = gr0 + rr;
        int gcol = gc0 - 16 + 4 * c4;
        unsigned word = 0u;
        if (grow < H && gcol >= 0 && gcol < W) {
            float4 f = *(const float4*)(xi + (size_t)grow * W + gcol);
            word = pack4(f, scale, nmb);
        }
        *(unsigned*)(tile + rr * TSTR + 4 * c4) = word;
    }
    __syncthreads();

    int r = tid >> 3;             // 0..31
    int c0 = (tid & 7) * 32;      // 0..224
    const unsigned char* rowp = tile + r * TSTR + 16 + c0;
    const unsigned char* wbase = tile + r * TSTR + c0;

    uint4 av0 = *(const uint4*)(rowp);
    uint4 av1 = *(const uint4*)(rowp + 16);
    unsigned aw[8];
    aw[0] = av0.x; aw[1] = av0.y; aw[2] = av0.z; aw[3] = av0.w;
    aw[4] = av1.x; aw[5] = av1.y; aw[6] = av1.z; aw[7] = av1.w;

    int acc[NACC];
#pragma unroll
    for (int k = 0; k < NACC; ++k) acc[k] = 0;
#pragma unroll
    for (int m = 0; m < 8; ++m) acc[16] = sdot4i(aw[m], aw[m], acc[16]);

    // two window buffers: delta k+1's ds_reads overlap delta k's sdot4 chain
    unsigned w1[16], w2[16];
    {   // delta=0 : oc = 1,3,5,7 (w1[4..11]==aw) ; prefetch delta=1 into w2
        load16w(wbase + 1 * TSTR, w2);
#pragma unroll
        for (int i = 0; i < 8; ++i) w1[4 + i] = aw[i];
        uint4 t3 = *(const uint4*)(wbase + 48);
        w1[12] = t3.x; w1[13] = t3.y; w1[14] = t3.z; w1[15] = t3.w;
        acc[0]  = dot8<1>(w1, aw, acc[0]);
        acc[4]  = dot8<3>(w1, aw, acc[4]);
        acc[8]  = dot8<5>(w1, aw, acc[8]);
        acc[12] = dot8<7>(w1, aw, acc[12]);
    }
    {   // delta=1 (w2) ; prefetch delta=2 into w1
        load16w(wbase + 2 * TSTR, w1);
        acc[1] = dot8<1>(w2, aw, acc[1]);
        acc[2] = dot8<0>(w2, aw, acc[2]);
        acc[3] = dot8<-1>(w2, aw, acc[3]);
    }
    {   // delta=2 (w1) ; prefetch delta=3 into w2
        load8mid(wbase + 3 * TSTR, w2);
        acc[5] = dot8<2>(w1, aw, acc[5]);
        acc[7] = dot8<-2>(w1, aw, acc[7]);
    }
    {   // delta=3 (w2) ; prefetch delta=4 into w1
        load16w(wbase + 4 * TSTR, w1);
        acc[6] = dot8<0>(w2, aw, acc[6]);
    }
    {   // delta=4 (w1) ; prefetch delta=5 into w2
        load16w(wbase + 5 * TSTR, w2);
        acc[9]  = dot8<4>(w1, aw, acc[9]);
        acc[11] = dot8<-4>(w1, aw, acc[11]);
    }
    {   // delta=5 (w2) ; prefetch delta=7 into w1
        load8mid(wbase + 7 * TSTR, w1);
        acc[10] = dot8<0>(w2, aw, acc[10]);
        acc[13] = dot8<5>(w2, aw, acc[13]);
        acc[15] = dot8<-5>(w2, aw, acc[15]);
    }
    {   // delta=7 (w1)
        acc[14] = dot8<0>(w1, aw, acc[14]);
    }

    // wave reduce via DPP (no LDS serialization), lane 63 holds totals
    int wv = tid >> 6, lane = tid & 63;
#pragma unroll
    for (int k = 0; k < NACC; ++k) {
        int s = wave_sum(acc[k]);
        if (lane == 63) wsum[wv][k] = s;
    }

    // border band sums of s^2 from staged tile
    if (rowTop || rowBot) {
        int base = rowTop ? 0 : (TH - 7);
        for (int idx = tid; idx < 7 * 64; idx += 256) {
            int rr = idx >> 6, ww = idx & 63;
            unsigned v = *(const unsigned*)(tile + (base + rr) * TSTR + 16 + 4 * ww);
            atomicAdd(&sRB[rr], sdot4i(v, v, 0));
        }
    }
    if (colLft || colRgt) {
        int cb = colLft ? 16 : 265;
        if (tid < 7 * TH) {
            int rr = tid / 7, j = tid - rr * 7;
            int s = (int)(signed char)tile[rr * TSTR + cb + j];
            atomicAdd(&sCB[j], s * s);
        }
    }
    // corner 7x7 s^2 patches -> ws (0=TL,1=TR,2=BL,3=BR, oriented to corner)
    if (tid < 49) {
        int i = tid / 7, j = tid - i * 7;
        if (rowTop && colLft) {
            int s = (int)(signed char)tile[i * TSTR + 16 + j];
            cornerWS[(img * 4 + 0) * 49 + tid] = (short)(s * s);
        }
        if (rowTop && colRgt) {
            int s = (int)(signed char)tile[i * TSTR + 271 - j];
            cornerWS[(img * 4 + 1) * 49 + tid] = (short)(s * s);
        }
        if (rowBot && colLft) {
            int s = (int)(signed char)tile[(TH - 1 - i) * TSTR + 16 + j];
            cornerWS[(img * 4 + 2) * 49 + tid] = (short)(s * s);
        }
        if (rowBot && colRgt) {
            int s = (int)(signed char)tile[(TH - 1 - i) * TSTR + 271 - j];
            cornerWS[(img * 4 + 3) * 49 + tid] = (short)(s * s);
        }
    }
    __syncthreads();
    if (tid < NACC) {
        int s = wsum[0][tid] + wsum[1][tid] + wsum[2][tid] + wsum[3][tid];
        atomicAdd(&gacc[img * NACC + tid], (unsigned long long)(long long)s);
    }
    if (tid < 7) {
        if (rowTop) atomicAdd(&RowS[img * 14 + tid], sRB[tid]);
        if (rowBot) atomicAdd(&RowS[img * 14 + 7 + tid], sRB[tid]);
        if (colLft) atomicAdd(&ColS[img * 14 + tid], sCB[tid]);
        if (colRgt) atomicAdd(&ColS[img * 14 + 7 + tid], sCB[tid]);
    }
}

// ---------------- kernel 3: combine (1 block, ~5 us incl. launch) -------------
__global__ __launch_bounds__(512)
void finalize_k(const unsigned long long* __restrict__ gacc,
                const int* __restrict__ RowS, const int* __restrict__ ColS,
                const short* __restrict__ cornerWS, float* __restrict__ out) {
    int tid = threadIdx.x;
    if (tid >= NIMG * NOFF) return;
    const int ORO[16] = {0,1,1,1, 0,2,3,2, 0,4,5,4, 0,5,7,5};
    const int OCO[16] = {1,1,0,-1, 3,2,0,-2, 5,4,0,-4, 7,5,0,-5};
    int im = tid >> 4, k = tid & 15;
    int orr = ORO[k], oc = OCO[k], aoc = oc < 0 ? -oc : oc;
    long long RT = 0, RB = 0, CL = 0, CR = 0;
    for (int i = 0; i < orr; ++i) {
        RT += RowS[im * 14 + i];
        RB += RowS[im * 14 + 13 - i];
    }
    for (int i = 0; i < aoc; ++i) {
        CL += ColS[im * 14 + i];
        CR += ColS[im * 14 + 13 - i];
    }
    long long CA = oc > 0 ? CR : CL;
    long long CB = oc > 0 ? CL : CR;
    const short* pa = cornerWS + (im * 4 + (oc >= 0 ? 3 : 2)) * 49;
    const short* pb = cornerWS + (im * 4 + (oc >= 0 ? 0 : 1)) * 49;
    long long PSa = 0, PSb = 0;
    for (int i = 0; i < orr; ++i)
        for (int j = 0; j < aoc; ++j) {
            PSa += pa[i * 7 + j];
            PSb += pb[i * 7 + j];
        }
    long long corr = -(RT + RB + CA + CB) + PSa + PSb;
    long long cross = (long long)gacc[im * NACC + k];
    long long tsum  = (long long)gacc[im * NACC + 16];
    long long num = 2 * tsum + corr - 2 * cross;
    double n = (double)(H - orr) * (double)(W - aoc);
    out[tid] = (float)((double)num / n);
}

extern "C" void kernel_launch(void* const* d_in, const int* in_sizes, int n_in,
                              void* d_out, int out_size, void* d_ws, size_t ws_size,
                              hipStream_t stream) {
    const float* x = (const float*)d_in[0];
    float* out = (float*)d_out;
    char* ws = (char*)d_ws;
    float* pmn = (float*)ws;                                       // 2048 f   @0
    float* pmx = (float*)(ws + 8192);                              // 2048 f   @8192
    unsigned long long* gacc = (unsigned long long*)(ws + 16384);  // 32*17 u64
    int* RowS = (int*)(ws + 20736);                                // 32*14 int
    int* ColS = (int*)(ws + 22528);                                // 32*14 int
    short* cornerWS = (short*)(ws + 24576);                        // 32*4*49 short

    minmax_partial<<<dim3(64, NIMG), 256, 0, stream>>>(x, pmn, pmx, gacc, RowS, ColS);
    glcm_main<<<dim3(4, 32, NIMG), 256, 0, stream>>>(x, pmn, pmx, gacc, RowS,
                                                     ColS, cornerWS);
    finalize_k<<<1, 512, 0, stream>>>(gacc, RowS, ColS, cornerWS, out);
}